// Round 2
// baseline (132814.270 us; speedup 1.0000x reference)
//
#include <hip/hip_runtime.h>
#include <hip/hip_cooperative_groups.h>
#include <math.h>

namespace cg = cooperative_groups;

#define T_STEPS 2048
#define BATCH   64
#define HDIM    512
#define GDIM    2048   // 4*H
#define INDIM   256
#define NBLK_RE 128    // recurrence workgroups

__device__ __forceinline__ float sigf(float x) { return 1.0f / (1.0f + __expf(-x)); }
__device__ __forceinline__ float tanh_fast(float x) {
    return 1.0f - 2.0f / (__expf(2.0f * x) + 1.0f);
}

// ---------------------------------------------------------------------------
// GEMM: C[t][n][b] = sum_k A(m=t*64+b, k) * Bw[n][k] + bias1[n] + bias2[n]
// A M-major: A[m][K] (layer-1 input x chunk). A K-major: A[t][k][64] (h chunk).
// Tile 128x128, 256 threads, 8x8 micro-tile, BK=32. m is chunk-relative.
// ---------------------------------------------------------------------------
template <int K, bool AKMAJ>
__global__ __launch_bounds__(256) void gemm_xg(
    const float* __restrict__ A, const float* __restrict__ Bw,
    const float* __restrict__ bias1, const float* __restrict__ bias2,
    float* __restrict__ C)
{
    constexpr int BK = 32;
    __shared__ float As[BK][128];
    __shared__ float Bs[BK][128];
    const int tid = threadIdx.x;
    const int n0 = blockIdx.x * 128;
    const int m0 = blockIdx.y * 128;

    float acc[8][8];
#pragma unroll
    for (int i = 0; i < 8; i++)
#pragma unroll
        for (int j = 0; j < 8; j++) acc[i][j] = 0.0f;

    for (int k0 = 0; k0 < K; k0 += BK) {
        if (!AKMAJ) {
#pragma unroll
            for (int l = 0; l < 4; l++) {
                int slot = tid + l * 256;       // 1024 float4 slots
                int row = slot >> 3, k4 = slot & 7;
                const float4 v = *(const float4*)&A[(size_t)(m0 + row) * K + k0 + k4 * 4];
                As[k4 * 4 + 0][row] = v.x; As[k4 * 4 + 1][row] = v.y;
                As[k4 * 4 + 2][row] = v.z; As[k4 * 4 + 3][row] = v.w;
            }
        } else {
#pragma unroll
            for (int l = 0; l < 4; l++) {
                int slot = tid + l * 256;
                int b4 = slot & 15, tt = (slot >> 4) & 1, kk = slot >> 5;
                int t = (m0 >> 6) + tt;
                const float4 v = *(const float4*)&A[((size_t)t * HDIM + k0 + kk) * BATCH + b4 * 4];
                int m = tt * 64 + b4 * 4;
                As[kk][m + 0] = v.x; As[kk][m + 1] = v.y;
                As[kk][m + 2] = v.z; As[kk][m + 3] = v.w;
            }
        }
#pragma unroll
        for (int l = 0; l < 4; l++) {
            int slot = tid + l * 256;
            int row = slot >> 3, k4 = slot & 7;
            const float4 v = *(const float4*)&Bw[(size_t)(n0 + row) * K + k0 + k4 * 4];
            Bs[k4 * 4 + 0][row] = v.x; Bs[k4 * 4 + 1][row] = v.y;
            Bs[k4 * 4 + 2][row] = v.z; Bs[k4 * 4 + 3][row] = v.w;
        }
        __syncthreads();

        const int tm = (tid & 15) * 8, tn = (tid >> 4) * 8;
#pragma unroll
        for (int kk = 0; kk < BK; kk++) {
            float a[8], b[8];
            *(float4*)&a[0] = *(float4*)&As[kk][tm];
            *(float4*)&a[4] = *(float4*)&As[kk][tm + 4];
            *(float4*)&b[0] = *(float4*)&Bs[kk][tn];
            *(float4*)&b[4] = *(float4*)&Bs[kk][tn + 4];
#pragma unroll
            for (int i = 0; i < 8; i++)
#pragma unroll
                for (int j = 0; j < 8; j++) acc[i][j] += a[i] * b[j];
        }
        __syncthreads();
    }

    const int tm = (tid & 15) * 8, tn = (tid >> 4) * 8;
    float bs[8];
#pragma unroll
    for (int j = 0; j < 8; j++) {
        int n = n0 + tn + j;
        bs[j] = bias1[n] + bias2[n];
    }
#pragma unroll
    for (int i = 0; i < 8; i++) {
        int m = m0 + tm + i;
        int t = m >> 6, b = m & 63;
#pragma unroll
        for (int j = 0; j < 8; j++) {
            int n = n0 + tn + j;
            C[((size_t)t * GDIM + n) * BATCH + b] = acc[i][j] + bs[j];
        }
    }
}

// ---------------------------------------------------------------------------
// Cooperative weights-stationary LSTM recurrence over one time chunk.
// 128 WGs x 256 threads. WG w owns h-dims j0=4w..4w+3 -> 16 gate rows
// r = gate*512 + j0 + d (gate order i,f,g,o). W slice (32 KB) in LDS once.
// hbuf layout [nsteps+1][512][64]; slot 0 = h from previous chunk (or zeros).
// Step t reads hbuf[t], writes hbuf[t+1]. c state persists in cst[512][64].
// After the chunk, h[nsteps] is copied to slot 0 for the next chunk.
// ---------------------------------------------------------------------------
__global__ __launch_bounds__(256) void lstm_coop(
    const float* __restrict__ xg,   // [nsteps][2048][64] chunk-relative
    const float* __restrict__ Whh,  // [2048][512]
    float* __restrict__ hbuf,       // [nsteps+1][512][64]
    float* __restrict__ cst,        // [512][64]
    int nsteps)
{
    cg::grid_group grid = cg::this_grid();
    __shared__ float Wl[16][HDIM];   // 32 KB
    __shared__ float hl[64][BATCH];  // 16 KB
    __shared__ float gl[16][BATCH];  // 4 KB

    const int tid = threadIdx.x;
    const int w = blockIdx.x;
    const int j0 = w * 4;

    // Preload W rows into LDS: 16 rows * 512 floats = 2048 float4
#pragma unroll
    for (int l = 0; l < 8; l++) {
        int slot = tid + l * 256;
        int lr = slot >> 7;          // 128 float4 per row
        int k4 = slot & 127;
        int r = (lr >> 2) * HDIM + j0 + (lr & 3);
        *(float4*)&Wl[lr][k4 * 4] = *(const float4*)&Whh[(size_t)r * HDIM + k4 * 4];
    }
    __syncthreads();

    const int rp = tid >> 5, bp = tid & 31;
    const int b0 = 2 * bp;
    const int lr0 = 2 * rp, lr1 = 2 * rp + 1;
    const int r0 = (lr0 >> 2) * HDIM + j0 + (lr0 & 3);
    const int r1 = (lr1 >> 2) * HDIM + j0 + (lr1 & 3);
    const int du = tid >> 6;   // h/c-update: dim j0+du, batch bu
    const int bu = tid & 63;
    float c_reg = cst[(size_t)(j0 + du) * BATCH + bu];
    float h_last = 0.0f;

    for (int t = 0; t < nsteps; t++) {
        float2 a0 = *(const float2*)&xg[((size_t)t * GDIM + r0) * BATCH + b0];
        float2 a1 = *(const float2*)&xg[((size_t)t * GDIM + r1) * BATCH + b0];

        const float* hprev = &hbuf[(size_t)t * HDIM * BATCH];
        for (int c8 = 0; c8 < 8; c8++) {
            __syncthreads();  // protect hl from previous chunk's readers
#pragma unroll
            for (int l = 0; l < 4; l++) {
                int slot = tid + l * 256;        // 1024 float4 = 64k x 64b
                int kk = slot >> 4, b4 = slot & 15;
                *(float4*)&hl[kk][b4 * 4] =
                    *(const float4*)&hprev[(size_t)(c8 * 64 + kk) * BATCH + b4 * 4];
            }
            __syncthreads();
            const int kg0 = c8 * 64;
#pragma unroll
            for (int kk = 0; kk < 64; kk += 4) {
                const float4 w0 = *(const float4*)&Wl[lr0][kg0 + kk];
                const float4 w1 = *(const float4*)&Wl[lr1][kg0 + kk];
                const float2 ha = *(const float2*)&hl[kk + 0][b0];
                const float2 hb = *(const float2*)&hl[kk + 1][b0];
                const float2 hc = *(const float2*)&hl[kk + 2][b0];
                const float2 hd = *(const float2*)&hl[kk + 3][b0];
                a0.x += w0.x * ha.x + w0.y * hb.x + w0.z * hc.x + w0.w * hd.x;
                a0.y += w0.x * ha.y + w0.y * hb.y + w0.z * hc.y + w0.w * hd.y;
                a1.x += w1.x * ha.x + w1.y * hb.x + w1.z * hc.x + w1.w * hd.x;
                a1.y += w1.x * ha.y + w1.y * hb.y + w1.z * hc.y + w1.w * hd.y;
            }
        }

        // gate exchange
        __syncthreads();
        *(float2*)&gl[lr0][b0] = a0;
        *(float2*)&gl[lr1][b0] = a1;
        __syncthreads();

        // h/c update: one (dim,batch) per thread
        {
            float gi = gl[0 + du][bu];
            float gf = gl[4 + du][bu];
            float gg = gl[8 + du][bu];
            float go = gl[12 + du][bu];
            c_reg = sigf(gf) * c_reg + sigf(gi) * tanh_fast(gg);
            float h = sigf(go) * tanh_fast(c_reg);
            hbuf[((size_t)(t + 1) * HDIM + j0 + du) * BATCH + bu] = h;
            h_last = h;
        }
        grid.sync();
    }

    // persist state for next chunk
    cst[(size_t)(j0 + du) * BATCH + bu] = c_reg;
    hbuf[(size_t)(j0 + du) * BATCH + bu] = h_last;   // slot 0
}

// ---------------------------------------------------------------------------
// Output: out[t*64+b] = sigmoid(sum_k Wout[k]*h2[t][k][b] + bout)
// h2 points at chunk slot 1 (nsteps slots). out pre-offset by t0*64.
// ---------------------------------------------------------------------------
__global__ __launch_bounds__(256) void out_kernel(
    const float* __restrict__ h2, const float* __restrict__ Wout,
    const float* __restrict__ bout, float* __restrict__ out)
{
    const int t = blockIdx.x;
    const int q = threadIdx.x >> 6, b = threadIdx.x & 63;
    const float* base = &h2[(size_t)t * HDIM * BATCH];
    float s = 0.0f;
#pragma unroll 4
    for (int k = q * 128; k < q * 128 + 128; k++)
        s += Wout[k] * base[(size_t)k * BATCH + b];
    __shared__ float red[4][64];
    red[q][b] = s;
    __syncthreads();
    if (q == 0) {
        float v = red[0][b] + red[1][b] + red[2][b] + red[3][b] + bout[0];
        out[t * BATCH + b] = sigf(v);
    }
}

// ---------------------------------------------------------------------------
static size_t req_bytes(int C) {
    // xg chunk (reused by both layers) + 2 h chunk buffers (+1 carry slot)
    // + 2 c-state buffers
    return 4ull * ((size_t)C * GDIM * BATCH
                   + 2ull * (size_t)(C + 1) * HDIM * BATCH
                   + 2ull * (size_t)HDIM * BATCH);
}

extern "C" void kernel_launch(void* const* d_in, const int* in_sizes, int n_in,
                              void* d_out, int out_size, void* d_ws, size_t ws_size,
                              hipStream_t stream)
{
    const float* x    = (const float*)d_in[0];
    const float* Wih1 = (const float*)d_in[1];
    const float* Whh1 = (const float*)d_in[2];
    const float* bih1 = (const float*)d_in[3];
    const float* bhh1 = (const float*)d_in[4];
    const float* Wih2 = (const float*)d_in[5];
    const float* Whh2 = (const float*)d_in[6];
    const float* bih2 = (const float*)d_in[7];
    const float* bhh2 = (const float*)d_in[8];
    const float* Wout = (const float*)d_in[9];
    const float* bout = (const float*)d_in[10];
    float* out = (float*)d_out;

    // pick largest chunk that fits the workspace (deterministic per call)
    int C = 8;
    const int cands[] = {2048, 1024, 512, 256, 128, 64, 32, 16, 8};
    for (int i = 0; i < 9; i++) {
        if (req_bytes(cands[i]) <= ws_size) { C = cands[i]; break; }
    }

    float* xg  = (float*)d_ws;                                   // C*2048*64
    float* h1b = xg  + (size_t)C * GDIM * BATCH;                 // (C+1)*512*64
    float* h2b = h1b + (size_t)(C + 1) * HDIM * BATCH;           // (C+1)*512*64
    float* c1  = h2b + (size_t)(C + 1) * HDIM * BATCH;           // 512*64
    float* c2  = c1  + (size_t)HDIM * BATCH;                     // 512*64

    // zero carry state (ws is poisoned 0xAA before every call)
    hipMemsetAsync(c1,  0, 2ull * HDIM * BATCH * 4, stream);     // c1+c2 contiguous
    hipMemsetAsync(h1b, 0, (size_t)HDIM * BATCH * 4, stream);    // h1 slot 0
    hipMemsetAsync(h2b, 0, (size_t)HDIM * BATCH * 4, stream);    // h2 slot 0

    int nsteps = C;
    const float* h1r = h1b + (size_t)HDIM * BATCH;  // chunk slots 1..C
    const float* h2r = h2b + (size_t)HDIM * BATCH;

    for (int t0 = 0; t0 < T_STEPS; t0 += C) {
        // xg1 = x_chunk @ Wih1^T + b (A M-major, K=256)
        gemm_xg<INDIM, false><<<dim3(GDIM / 128, C * BATCH / 128), dim3(256), 0, stream>>>(
            x + (size_t)t0 * BATCH * INDIM, Wih1, bih1, bhh1, xg);

        {
            void* args[] = {(void*)&xg, (void*)&Whh1, (void*)&h1b, (void*)&c1, (void*)&nsteps};
            hipLaunchCooperativeKernel((void*)lstm_coop, dim3(NBLK_RE), dim3(256), args, 0, stream);
        }

        // xg2 = h1_chunk @ Wih2^T + b (A K-major, K=512) — overwrites xg
        gemm_xg<HDIM, true><<<dim3(GDIM / 128, C * BATCH / 128), dim3(256), 0, stream>>>(
            h1r, Wih2, bih2, bhh2, xg);

        {
            void* args[] = {(void*)&xg, (void*)&Whh2, (void*)&h2b, (void*)&c2, (void*)&nsteps};
            hipLaunchCooperativeKernel((void*)lstm_coop, dim3(NBLK_RE), dim3(256), args, 0, stream);
        }

        out_kernel<<<dim3(C), dim3(256), 0, stream>>>(h2r, Wout, bout, out + (size_t)t0 * BATCH);
    }

    (void)in_sizes; (void)n_in; (void)out_size;
}

// Round 3
// 35780.939 us; speedup vs baseline: 3.7119x; 3.7119x over previous
//
#include <hip/hip_runtime.h>
#include <math.h>

#define T_STEPS 2048
#define BATCH   64
#define HDIM    512
#define GDIM    2048   // 4*H
#define INDIM   256
#define NBLK_RE 128    // recurrence workgroups (1 per 4 h-dims)

typedef _Float16 f16x8 __attribute__((ext_vector_type(8)));
typedef _Float16 f16x4 __attribute__((ext_vector_type(4)));
typedef float    f32x4 __attribute__((ext_vector_type(4)));

__device__ __forceinline__ float sigf(float x) { return 1.0f / (1.0f + __expf(-x)); }
__device__ __forceinline__ float tanh_fast(float x) {
    return 1.0f - 2.0f / (__expf(2.0f * x) + 1.0f);   // saturates correctly
}

// ---------------------------------------------------------------------------
// fp32 -> fp16 weight conversion (once per launch; 2 MB each)
// ---------------------------------------------------------------------------
__global__ __launch_bounds__(256) void cvt_f16(const float* __restrict__ src,
                                               _Float16* __restrict__ dst, int n4)
{
    int i = blockIdx.x * 256 + threadIdx.x;
    if (i < n4) {
        float4 v = ((const float4*)src)[i];
        f16x4 h;
        h[0] = (_Float16)v.x; h[1] = (_Float16)v.y;
        h[2] = (_Float16)v.z; h[3] = (_Float16)v.w;
        ((f16x4*)dst)[i] = h;
    }
}

// ---------------------------------------------------------------------------
// GEMM: C[t][n][b] = sum_k A(m=t*64+b, k) * Bw[n][k] + bias1[n] + bias2[n]
// A M-major fp32 (layer-1 x) or M-major fp16 (h1 history). Tile 128x128,
// 256 threads, 8x8 micro-tile, BK=32.
// ---------------------------------------------------------------------------
template <int K, bool AF16>
__global__ __launch_bounds__(256) void gemm_xg(
    const void* __restrict__ Araw, const float* __restrict__ Bw,
    const float* __restrict__ bias1, const float* __restrict__ bias2,
    float* __restrict__ C)
{
    constexpr int BK = 32;
    __shared__ float As[BK][128];
    __shared__ float Bs[BK][128];
    const int tid = threadIdx.x;
    const int n0 = blockIdx.x * 128;
    const int m0 = blockIdx.y * 128;

    float acc[8][8];
#pragma unroll
    for (int i = 0; i < 8; i++)
#pragma unroll
        for (int j = 0; j < 8; j++) acc[i][j] = 0.0f;

    for (int k0 = 0; k0 < K; k0 += BK) {
#pragma unroll
        for (int l = 0; l < 4; l++) {
            int slot = tid + l * 256;       // 1024 slots = 128 rows x 8 k-quads
            int row = slot >> 3, k4 = slot & 7;
            if (!AF16) {
                const float4 v = *(const float4*)
                    ((const float*)Araw + (size_t)(m0 + row) * K + k0 + k4 * 4);
                As[k4 * 4 + 0][row] = v.x; As[k4 * 4 + 1][row] = v.y;
                As[k4 * 4 + 2][row] = v.z; As[k4 * 4 + 3][row] = v.w;
            } else {
                const uint2 u = *(const uint2*)
                    ((const _Float16*)Araw + (size_t)(m0 + row) * K + k0 + k4 * 4);
                f16x4 h = __builtin_bit_cast(f16x4, u);
                As[k4 * 4 + 0][row] = (float)h[0]; As[k4 * 4 + 1][row] = (float)h[1];
                As[k4 * 4 + 2][row] = (float)h[2]; As[k4 * 4 + 3][row] = (float)h[3];
            }
        }
#pragma unroll
        for (int l = 0; l < 4; l++) {
            int slot = tid + l * 256;
            int row = slot >> 3, k4 = slot & 7;
            const float4 v = *(const float4*)&Bw[(size_t)(n0 + row) * K + k0 + k4 * 4];
            Bs[k4 * 4 + 0][row] = v.x; Bs[k4 * 4 + 1][row] = v.y;
            Bs[k4 * 4 + 2][row] = v.z; Bs[k4 * 4 + 3][row] = v.w;
        }
        __syncthreads();

        const int tm = (tid & 15) * 8, tn = (tid >> 4) * 8;
#pragma unroll
        for (int kk = 0; kk < BK; kk++) {
            float a[8], b[8];
            *(float4*)&a[0] = *(float4*)&As[kk][tm];
            *(float4*)&a[4] = *(float4*)&As[kk][tm + 4];
            *(float4*)&b[0] = *(float4*)&Bs[kk][tn];
            *(float4*)&b[4] = *(float4*)&Bs[kk][tn + 4];
#pragma unroll
            for (int i = 0; i < 8; i++)
#pragma unroll
                for (int j = 0; j < 8; j++) acc[i][j] += a[i] * b[j];
        }
        __syncthreads();
    }

    const int tm = (tid & 15) * 8, tn = (tid >> 4) * 8;
    float bs[8];
#pragma unroll
    for (int j = 0; j < 8; j++) {
        int n = n0 + tn + j;
        bs[j] = bias1[n] + bias2[n];
    }
#pragma unroll
    for (int i = 0; i < 8; i++) {
        int m = m0 + tm + i;
        int t = m >> 6, b = m & 63;
#pragma unroll
        for (int j = 0; j < 8; j++) {
            int n = n0 + tn + j;
            C[((size_t)t * GDIM + n) * BATCH + b] = acc[i][j] + bs[j];
        }
    }
}

// ---------------------------------------------------------------------------
// MFMA f16 cooperative LSTM recurrence, weights-in-registers, sc1 barrier.
// 128 WGs x 256 thr. WG owns h-dims j0=4*wg..+3 -> 16 gate rows
// grow = (lr>>2)*512 + j0 + (lr&3), lr = 4*gate + dim. B-frags (W) pinned in
// VGPRs. Wave wv computes the 16x16 tile gates[b=16wv..+15][lr] by 16 MFMAs
// over K=512, A-frags loaded straight from global h (agent-scope/LLC).
// h layout: hbuf[(t)][b][512] fp16 (slot 0 = carry). Barrier: per-WG
// fetch_add after wave0's h-stores drained; all waves spin.
// ---------------------------------------------------------------------------
__global__ __launch_bounds__(256, 1) void lstm_mfma(
    const float* __restrict__ xg,        // [nsteps][2048][64]
    const _Float16* __restrict__ Wf,     // [2048][512]
    _Float16* __restrict__ hbuf,         // [nsteps+1][64][512]
    float* __restrict__ cst,             // [512][64]
    unsigned* __restrict__ ctr,          // one cell, zeroed
    int nsteps)
{
    __shared__ float    gl[16][68];      // gate exchange, padded
    __shared__ _Float16 hsm[64][4];      // packed h per batch

    const int tid  = threadIdx.x;
    const int wg   = blockIdx.x;
    const int j0   = wg * 4;
    const int wv   = tid >> 6;           // wave = M-tile
    const int ln   = tid & 63;
    const int l16  = ln & 15;
    const int quad = ln >> 4;

    // ---- pin B fragments (W rows) in registers ----
    const int grow = (l16 >> 2) * HDIM + j0 + (l16 & 3);
    f16x8 Bf[16];
#pragma unroll
    for (int j = 0; j < 16; j++) {
        const uint4 u = *(const uint4*)&Wf[(size_t)grow * HDIM + j * 32 + quad * 8];
        Bf[j] = __builtin_bit_cast(f16x8, u);
    }

    const int du = wv;                   // update thread: dim j0+du, batch bu
    const int bu = tid & 63;
    float c_reg = cst[(size_t)(j0 + du) * BATCH + bu];

    const size_t xoff0 = (size_t)(0 * HDIM + j0 + du) * BATCH + bu;
    const size_t xoff1 = (size_t)(1 * HDIM + j0 + du) * BATCH + bu;
    const size_t xoff2 = (size_t)(2 * HDIM + j0 + du) * BATCH + bu;
    const size_t xoff3 = (size_t)(3 * HDIM + j0 + du) * BATCH + bu;

    for (int t = 0; t < nsteps; t++) {
        // prefetch xg (regular cached loads; independent of barrier)
        const float* xgt = xg + (size_t)t * GDIM * BATCH;
        float x0 = xgt[xoff0], x1 = xgt[xoff1], x2 = xgt[xoff2], x3 = xgt[xoff3];

        // wait until all WGs published h[t] (t=0: carry slot, ready at launch)
        if (t > 0) {
            const unsigned tgt = (unsigned)(NBLK_RE * t);
            while (__hip_atomic_load(ctr, __ATOMIC_RELAXED,
                                     __HIP_MEMORY_SCOPE_AGENT) < tgt) {}
            __atomic_signal_fence(__ATOMIC_ACQUIRE);
        }

        // ---- A fragments straight from global (LLC-coherent loads) ----
        const _Float16* hp = hbuf + (size_t)t * (BATCH * HDIM)
                             + (size_t)(16 * wv + l16) * HDIM + quad * 8;
        unsigned long long alo[16], ahi[16];
#pragma unroll
        for (int j = 0; j < 16; j++) {
            alo[j] = __hip_atomic_load((const unsigned long long*)(hp + j * 32),
                                       __ATOMIC_RELAXED, __HIP_MEMORY_SCOPE_AGENT);
            ahi[j] = __hip_atomic_load((const unsigned long long*)(hp + j * 32 + 4),
                                       __ATOMIC_RELAXED, __HIP_MEMORY_SCOPE_AGENT);
        }

        f32x4 acc0 = {0.f, 0.f, 0.f, 0.f}, acc1 = {0.f, 0.f, 0.f, 0.f};
#pragma unroll
        for (int j = 0; j < 16; j += 2) {
            ulonglong2 p0; p0.x = alo[j];     p0.y = ahi[j];
            acc0 = __builtin_amdgcn_mfma_f32_16x16x32_f16(
                __builtin_bit_cast(f16x8, p0), Bf[j],     acc0, 0, 0, 0);
            ulonglong2 p1; p1.x = alo[j + 1]; p1.y = ahi[j + 1];
            acc1 = __builtin_amdgcn_mfma_f32_16x16x32_f16(
                __builtin_bit_cast(f16x8, p1), Bf[j + 1], acc1, 0, 0, 0);
        }
        f32x4 d = acc0 + acc1;
        // D layout: col(n)=lane&15 -> gate row lr; row(m)=quad*4+reg -> batch
        *(f32x4*)&gl[l16][16 * wv + quad * 4] = d;
        __syncthreads();

        // ---- pointwise update: one (dim, batch) per thread ----
        {
            float si = gl[4 * 0 + du][bu] + x0;
            float sf = gl[4 * 1 + du][bu] + x1;
            float sg = gl[4 * 2 + du][bu] + x2;
            float so = gl[4 * 3 + du][bu] + x3;
            c_reg = sigf(sf) * c_reg + sigf(si) * tanh_fast(sg);
            float h = sigf(so) * tanh_fast(c_reg);
            hsm[bu][du] = (_Float16)h;
        }
        __syncthreads();   // hsm ready; also protects gl before next D-write

        // ---- publish h (wave 0) + arrive ----
        if (tid < 64) {
            unsigned long long pk = *(const unsigned long long*)&hsm[tid][0];
            unsigned long long* dst = (unsigned long long*)
                (hbuf + (size_t)(t + 1) * (BATCH * HDIM) + (size_t)tid * HDIM + j0);
            __hip_atomic_store(dst, pk, __ATOMIC_RELAXED, __HIP_MEMORY_SCOPE_AGENT);
            if (t == nsteps - 1) {   // carry slot for next chunk
                unsigned long long* dst0 = (unsigned long long*)
                    (hbuf + (size_t)tid * HDIM + j0);
                __hip_atomic_store(dst0, pk, __ATOMIC_RELAXED, __HIP_MEMORY_SCOPE_AGENT);
            }
            if (tid == 0) {
                asm volatile("s_waitcnt vmcnt(0)" ::: "memory");  // h at LLC
                __hip_atomic_fetch_add(ctr, 1u, __ATOMIC_RELAXED,
                                       __HIP_MEMORY_SCOPE_AGENT);
            }
        }
    }

    cst[(size_t)(j0 + du) * BATCH + bu] = c_reg;
}

// ---------------------------------------------------------------------------
// out[t*64+b] = sigmoid(dot(Wout, h2[t][b][:]) + bout); h2 fp16 [t][b][512]
// ---------------------------------------------------------------------------
__global__ __launch_bounds__(256) void out_kernel(
    const _Float16* __restrict__ h2, const float* __restrict__ Wout,
    const float* __restrict__ bout, float* __restrict__ out)
{
    const int t = blockIdx.x;
    const int q = threadIdx.x >> 6, b = threadIdx.x & 63;
    const _Float16* base = &h2[(size_t)t * (BATCH * HDIM) + (size_t)b * HDIM];
    float s = 0.0f;
#pragma unroll 8
    for (int k = q * 128; k < q * 128 + 128; k += 4) {
        const uint2 u = *(const uint2*)&base[k];
        f16x4 h = __builtin_bit_cast(f16x4, u);
        s += Wout[k] * (float)h[0] + Wout[k + 1] * (float)h[1]
           + Wout[k + 2] * (float)h[2] + Wout[k + 3] * (float)h[3];
    }
    __shared__ float red[4][64];
    red[q][b] = s;
    __syncthreads();
    if (q == 0) {
        float v = red[0][b] + red[1][b] + red[2][b] + red[3][b] + bout[0];
        out[t * BATCH + b] = sigf(v);
    }
}

// ---------------------------------------------------------------------------
static size_t req_bytes(int C) {
    return 4096                                  // counters
         + 2ull * HDIM * BATCH * 4               // c1, c2
         + 2ull * GDIM * HDIM * 2                // Wf1, Wf2
         + 2ull * (size_t)(C + 1) * BATCH * HDIM * 2  // hbuf1, hbuf2
         + (size_t)C * GDIM * BATCH * 4;         // xg
}

extern "C" void kernel_launch(void* const* d_in, const int* in_sizes, int n_in,
                              void* d_out, int out_size, void* d_ws, size_t ws_size,
                              hipStream_t stream)
{
    const float* x    = (const float*)d_in[0];
    const float* Wih1 = (const float*)d_in[1];
    const float* Whh1 = (const float*)d_in[2];
    const float* bih1 = (const float*)d_in[3];
    const float* bhh1 = (const float*)d_in[4];
    const float* Wih2 = (const float*)d_in[5];
    const float* Whh2 = (const float*)d_in[6];
    const float* bih2 = (const float*)d_in[7];
    const float* bhh2 = (const float*)d_in[8];
    const float* Wout = (const float*)d_in[9];
    const float* bout = (const float*)d_in[10];
    float* out = (float*)d_out;

    int C = 8;
    const int cands[] = {2048, 1024, 512, 256, 128, 64, 32, 16, 8};
    for (int i = 0; i < 9; i++)
        if (req_bytes(cands[i]) <= ws_size) { C = cands[i]; break; }

    char* p = (char*)d_ws;
    unsigned*  ctr  = (unsigned*)p;                 p += 4096;
    float*     c1   = (float*)p;                    p += (size_t)HDIM * BATCH * 4;
    float*     c2   = (float*)p;                    p += (size_t)HDIM * BATCH * 4;
    _Float16*  Wf1  = (_Float16*)p;                 p += (size_t)GDIM * HDIM * 2;
    _Float16*  Wf2  = (_Float16*)p;                 p += (size_t)GDIM * HDIM * 2;
    _Float16*  hb1  = (_Float16*)p;                 p += (size_t)(C + 1) * BATCH * HDIM * 2;
    _Float16*  hb2  = (_Float16*)p;                 p += (size_t)(C + 1) * BATCH * HDIM * 2;
    float*     xg   = (float*)p;

    // zero counters + c-state (contiguous) and the two h carry slots
    hipMemsetAsync(ctr, 0, 4096 + 2ull * HDIM * BATCH * 4, stream);
    hipMemsetAsync(hb1, 0, (size_t)BATCH * HDIM * 2, stream);
    hipMemsetAsync(hb2, 0, (size_t)BATCH * HDIM * 2, stream);

    // fp16 weights
    cvt_f16<<<dim3(GDIM * HDIM / 4 / 256), dim3(256), 0, stream>>>(Whh1, Wf1, GDIM * HDIM / 4);
    cvt_f16<<<dim3(GDIM * HDIM / 4 / 256), dim3(256), 0, stream>>>(Whh2, Wf2, GDIM * HDIM / 4);

    const _Float16* h1r = hb1 + (size_t)BATCH * HDIM;   // slots 1..C
    const _Float16* h2r = hb2 + (size_t)BATCH * HDIM;
    int cidx = 0;

    for (int t0 = 0; t0 < T_STEPS; t0 += C, cidx += 2) {
        gemm_xg<INDIM, false><<<dim3(GDIM / 128, C * BATCH / 128), dim3(256), 0, stream>>>(
            x + (size_t)t0 * BATCH * INDIM, Wih1, bih1, bhh1, xg);

        {
            unsigned* c = ctr + cidx;
            void* args[] = {(void*)&xg, (void*)&Wf1, (void*)&hb1, (void*)&c1,
                            (void*)&c, (void*)&C};
            hipLaunchCooperativeKernel((void*)lstm_mfma, dim3(NBLK_RE), dim3(256),
                                       args, 0, stream);
        }

        gemm_xg<HDIM, true><<<dim3(GDIM / 128, C * BATCH / 128), dim3(256), 0, stream>>>(
            h1r, Wih2, bih2, bhh2, xg);

        {
            unsigned* c = ctr + cidx + 1;
            void* args[] = {(void*)&xg, (void*)&Wf2, (void*)&hb2, (void*)&c2,
                            (void*)&c, (void*)&C};
            hipLaunchCooperativeKernel((void*)lstm_mfma, dim3(NBLK_RE), dim3(256),
                                       args, 0, stream);
        }

        out_kernel<<<dim3(C), dim3(256), 0, stream>>>(h2r, Wout, bout,
                                                      out + (size_t)t0 * BATCH);
    }

    (void)in_sizes; (void)n_in; (void)out_size;
}